// Round 1
// baseline (254.086 us; speedup 1.0000x reference)
//
#include <hip/hip_runtime.h>
#include <hip/hip_fp16.h>
#include <math.h>

typedef _Float16 f16x8 __attribute__((ext_vector_type(8)));
typedef _Float16 f16x4 __attribute__((ext_vector_type(4)));
typedef float f32x4 __attribute__((ext_vector_type(4)));

#define DD     128     // d
#define D2     256     // 2d
#define NB     8192    // batch
#define NCLS   5
#define KV     65536   // 256*256
#define KBV    8192    // KV/8
#define KBTOT  8224    // KBV + 256/8 (W_w tail)
#define KSPLIT 8
#define BM     128
#define PPAD   264     // 256 + 8 f16 pad -> row stride 528B = 132 dw == 4 mod 32 banks

// ---------------- prep: V (fp32 [256][256][128]) -> Vt fp16 [kb][n][8] fragment layout;
//                  append W_w^T (B[KV+j][n] = W_w[n][j]) in the same layout ----------------
__global__ void prep_vt(const float* __restrict__ V, const float* __restrict__ Ww,
                        _Float16* __restrict__ Vt) {
    int t = blockIdx.x * 256 + threadIdx.x;   // one thread per (kb, n)
    if (t >= KBTOT * DD) return;
    int kb = t >> 7;
    int n  = t & 127;
    f16x8 v;
    if (kb < KBV) {
        #pragma unroll
        for (int e = 0; e < 8; ++e)
            v[e] = (_Float16)V[(size_t)(kb * 8 + e) * DD + n];
    } else {
        int j0 = (kb - KBV) * 8;
        #pragma unroll
        for (int e = 0; e < 8; ++e)
            v[e] = (_Float16)Ww[n * D2 + j0 + e];
    }
    *(f16x8*)(Vt + (size_t)t * 8) = v;
}

// ---------------- main: tp_partial[ks][b][k] via outer-product-A MFMA GEMM ----------------
__global__ __launch_bounds__(256) void gemm_bilinear(
        const float* __restrict__ left, const float* __restrict__ right,
        const _Float16* __restrict__ Vt, float* __restrict__ part) {
    __shared__ _Float16 P[BM][PPAD];

    const int bid = blockIdx.x;
    const int ks  = bid & 7;       // == XCD id under round-robin dispatch -> one V slice per XCD L2
    const int mt  = bid >> 3;
    const int m0  = mt * BM;
    const int tid = threadIdx.x;

    // stage phrase tile (fp32 global -> fp16 LDS), coalesced float4 reads
    for (int it = 0; it < 32; ++it) {
        int f4  = it * 256 + tid;          // float4 index over [128][256]
        int row = f4 >> 6;
        int col = (f4 & 63) * 4;
        const float* src = (col < DD) ? (left  + (size_t)(m0 + row) * DD + col)
                                      : (right + (size_t)(m0 + row) * DD + (col - DD));
        float4 x = *(const float4*)src;
        f16x4 hv;
        hv[0] = (_Float16)x.x; hv[1] = (_Float16)x.y;
        hv[2] = (_Float16)x.z; hv[3] = (_Float16)x.w;
        *(f16x4*)&P[row][col] = hv;
    }
    __syncthreads();

    const int lane = tid & 63;
    const int wid  = tid >> 6;
    const int wm   = wid >> 1, wn = wid & 1;   // 2x2 wave grid, 64x64 wave tile
    const int l15  = lane & 15, lg = lane >> 4;

    f32x4 acc[4][4];
    #pragma unroll
    for (int u = 0; u < 4; ++u)
        #pragma unroll
        for (int w = 0; w < 4; ++w)
            acc[u][w] = (f32x4){0.f, 0.f, 0.f, 0.f};

    // K-range of this split: i in [ks*32, ks*32+32), all j. No barriers in this loop.
    for (int ib = 0; ib < 32; ++ib) {
        const int i = ks * 32 + ib;
        _Float16 pis[4];
        #pragma unroll
        for (int mr = 0; mr < 4; ++mr)
            pis[mr] = P[wm * 64 + mr * 16 + l15][i];

        for (int jc = 0; jc < 8; ++jc) {
            const int kb = ks * 1024 + ib * 32 + jc * 4 + lg;
            f16x8 bfr[4];
            #pragma unroll
            for (int nr = 0; nr < 4; ++nr) {
                const int n = wn * 64 + nr * 16 + l15;
                bfr[nr] = *(const f16x8*)(Vt + (size_t)kb * 1024 + n * 8);
            }
            #pragma unroll
            for (int mr = 0; mr < 4; ++mr) {
                const f16x8 pj = *(const f16x8*)&P[wm * 64 + mr * 16 + l15][jc * 32 + lg * 8];
                f16x8 a;
                #pragma unroll
                for (int e = 0; e < 8; ++e) a[e] = pj[e] * pis[mr];   // -> v_pk_mul_f16
                #pragma unroll
                for (int nr = 0; nr < 4; ++nr)
                    acc[mr][nr] = __builtin_amdgcn_mfma_f32_16x16x32_f16(a, bfr[nr], acc[mr][nr], 0, 0, 0);
            }
        }
    }

    // last split also does the folded W_w matvec tail: A = P directly
    if (ks == KSPLIT - 1) {
        for (int jc = 0; jc < 8; ++jc) {
            const int kb = KBV + jc * 4 + lg;
            f16x8 bfr[4];
            #pragma unroll
            for (int nr = 0; nr < 4; ++nr) {
                const int n = wn * 64 + nr * 16 + l15;
                bfr[nr] = *(const f16x8*)(Vt + (size_t)kb * 1024 + n * 8);
            }
            #pragma unroll
            for (int mr = 0; mr < 4; ++mr) {
                const f16x8 a = *(const f16x8*)&P[wm * 64 + mr * 16 + l15][jc * 32 + lg * 8];
                #pragma unroll
                for (int nr = 0; nr < 4; ++nr)
                    acc[mr][nr] = __builtin_amdgcn_mfma_f32_16x16x32_f16(a, bfr[nr], acc[mr][nr], 0, 0, 0);
            }
        }
    }

    // write fp32 partials; C/D layout: col = lane&15, row = (lane>>4)*4 + q  [m89-verified]
    float* base = part + ((size_t)ks * NB + m0) * DD;
    #pragma unroll
    for (int mr = 0; mr < 4; ++mr)
        #pragma unroll
        for (int nr = 0; nr < 4; ++nr) {
            const int col = wn * 64 + nr * 16 + l15;
            #pragma unroll
            for (int q = 0; q < 4; ++q) {
                const int row = wm * 64 + mr * 16 + lg * 4 + q;
                base[(size_t)row * DD + col] = acc[mr][nr][q];
            }
        }
}

// ---------------- epilogue: reduce splits, +W_b, tanh, 5-class logits, log_softmax --------
__global__ void finish(const float* __restrict__ part, const float* __restrict__ Wb,
                       const float* __restrict__ Wsw, const float* __restrict__ Wsb,
                       float* __restrict__ out) {
    int b = blockIdx.x * 256 + threadIdx.x;
    if (b >= NB) return;
    float lg[NCLS];
    #pragma unroll
    for (int c = 0; c < NCLS; ++c) lg[c] = Wsb[c];

    for (int k4 = 0; k4 < DD / 4; ++k4) {
        float4 t = *(const float4*)(Wb + k4 * 4);
        #pragma unroll
        for (int s = 0; s < KSPLIT; ++s) {
            float4 p = *(const float4*)(part + ((size_t)s * NB + b) * DD + k4 * 4);
            t.x += p.x; t.y += p.y; t.z += p.z; t.w += p.w;
        }
        float tq[4] = {t.x, t.y, t.z, t.w};
        #pragma unroll
        for (int q = 0; q < 4; ++q) {
            float h = tanhf(tq[q]);
            int k = k4 * 4 + q;
            #pragma unroll
            for (int c = 0; c < NCLS; ++c)
                lg[c] += h * Wsw[c * DD + k];
        }
    }
    float mx = lg[0];
    #pragma unroll
    for (int c = 1; c < NCLS; ++c) mx = fmaxf(mx, lg[c]);
    float s = 0.f;
    #pragma unroll
    for (int c = 0; c < NCLS; ++c) s += expf(lg[c] - mx);
    float lse = logf(s);
    #pragma unroll
    for (int c = 0; c < NCLS; ++c) out[b * NCLS + c] = lg[c] - mx - lse;
}

extern "C" void kernel_launch(void* const* d_in, const int* in_sizes, int n_in,
                              void* d_out, int out_size, void* d_ws, size_t ws_size,
                              hipStream_t stream) {
    const float* left  = (const float*)d_in[0];
    const float* right = (const float*)d_in[1];
    const float* V     = (const float*)d_in[2];
    const float* Ww    = (const float*)d_in[3];
    const float* Wb    = (const float*)d_in[4];
    const float* Wsw   = (const float*)d_in[5];
    const float* Wsb   = (const float*)d_in[6];
    float* out = (float*)d_out;

    _Float16* Vt = (_Float16*)d_ws;                                  // 16,842,752 B
    float* part  = (float*)((char*)d_ws + (size_t)KBTOT * 1024 * 2); // 33,554,432 B

    hipLaunchKernelGGL(prep_vt, dim3((KBTOT * DD) / 256), dim3(256), 0, stream, V, Ww, Vt);
    hipLaunchKernelGGL(gemm_bilinear, dim3((NB / BM) * KSPLIT), dim3(256), 0, stream,
                       left, right, Vt, part);
    hipLaunchKernelGGL(finish, dim3(NB / 256), dim3(256), 0, stream, part, Wb, Wsw, Wsb, out);
}

// Round 2
// 175.209 us; speedup vs baseline: 1.4502x; 1.4502x over previous
//
#include <hip/hip_runtime.h>
#include <hip/hip_fp16.h>
#include <math.h>

typedef _Float16 f16x8 __attribute__((ext_vector_type(8)));
typedef _Float16 f16x4 __attribute__((ext_vector_type(4)));
typedef float f32x4 __attribute__((ext_vector_type(4)));

#define DD     128     // d
#define D2     256     // 2d
#define NB     8192    // batch
#define NCLS   5
#define KBV    8192    // 65536/8 k-blocks of 8
#define KBTOT  8224    // KBV + 256/8 (W_w tail)
#define KSPLIT 8
#define BM     128
#define PPAD   258     // row stride 516B = 129 dw == 1 mod 32 -> conflict-free

// ---------------- prep: V (fp32 [256][256][128]) -> Vt fp16 [kb][n][8] fragment layout;
//                  append W_w^T (B[KV+j][n] = W_w[n][j]) in the same layout ----------------
__global__ void prep_vt(const float* __restrict__ V, const float* __restrict__ Ww,
                        _Float16* __restrict__ Vt) {
    int t = blockIdx.x * 256 + threadIdx.x;   // one thread per (kb, n)
    if (t >= KBTOT * DD) return;
    int kb = t >> 7;
    int n  = t & 127;
    f16x8 v;
    if (kb < KBV) {
        #pragma unroll
        for (int e = 0; e < 8; ++e)
            v[e] = (_Float16)V[(size_t)(kb * 8 + e) * DD + n];
    } else {
        int j0 = (kb - KBV) * 8;
        #pragma unroll
        for (int e = 0; e < 8; ++e)
            v[e] = (_Float16)Ww[n * D2 + j0 + e];
    }
    *(f16x8*)(Vt + (size_t)t * 8) = v;
}

// ---------------- main: tp_partial[ks][b][k] via outer-product-A MFMA GEMM ----------------
__global__ __launch_bounds__(256, 2) void gemm_bilinear(
        const float* __restrict__ left, const float* __restrict__ right,
        const _Float16* __restrict__ Vt, float* __restrict__ part) {
    __shared__ _Float16 P[BM][PPAD];

    const int bid = blockIdx.x;
    const int ks  = bid & 7;       // == XCD id under round-robin dispatch -> one V slice per XCD L2
    const int m0  = (bid >> 3) * BM;
    const int tid = threadIdx.x;

    // stage phrase tile (fp32 global -> fp16 LDS), coalesced float4 reads
    for (int it = 0; it < 32; ++it) {
        int f4  = it * 256 + tid;          // float4 index over [128][256]
        int row = f4 >> 6;
        int col = (f4 & 63) * 4;
        const float* src = (col < DD) ? (left  + (size_t)(m0 + row) * DD + col)
                                      : (right + (size_t)(m0 + row) * DD + (col - DD));
        float4 x = *(const float4*)src;
        f16x4 hv;
        hv[0] = (_Float16)x.x; hv[1] = (_Float16)x.y;
        hv[2] = (_Float16)x.z; hv[3] = (_Float16)x.w;
        *(f16x4*)&P[row][col] = hv;
    }
    __syncthreads();

    const int lane = tid & 63;
    const int wid  = tid >> 6;
    const int wm   = wid >> 1, wn = wid & 1;   // 2x2 wave grid, 64x64 wave tile
    const int l15  = lane & 15, lg = lane >> 4;
    const int rowb = wm * 64;
    const int coln = wn * 64;

    f32x4 acc[4][4];
    #pragma unroll
    for (int u = 0; u < 4; ++u)
        #pragma unroll
        for (int w = 0; w < 4; ++w)
            acc[u][w] = (f32x4){0.f, 0.f, 0.f, 0.f};

    // per-lane element base into Vt: kb = ks*1024 + lg (+ib*32 +jc*4), n = coln + l15 (+nr*16)
    const _Float16* vbase = Vt + ((size_t)(ks * 1024 + lg) * 128 + coln + l15) * 8;

    // K-range of this split: i in [ks*32, ks*32+32), all j. No barriers in this loop.
    #pragma unroll 1
    for (int jc2 = 0; jc2 < 4; ++jc2) {
        // hoist A j-fragments for this jc pair into registers (invariant over ib)
        f16x8 pjA[4], pjB[4];
        #pragma unroll
        for (int mr = 0; mr < 4; ++mr) {
            pjA[mr] = *(const f16x8*)&P[rowb + mr * 16 + l15][(jc2 * 2 + 0) * 32 + lg * 8];
            pjB[mr] = *(const f16x8*)&P[rowb + mr * 16 + l15][(jc2 * 2 + 1) * 32 + lg * 8];
        }
        #pragma unroll 1
        for (int ibc = 0; ibc < 4; ++ibc) {
            // i-values for this chunk, vectorized (same addr across lg -> LDS broadcast)
            f16x8 pis[4];
            #pragma unroll
            for (int mr = 0; mr < 4; ++mr)
                pis[mr] = *(const f16x8*)&P[rowb + mr * 16 + l15][ks * 32 + ibc * 8];

            #pragma unroll
            for (int ibe = 0; ibe < 8; ++ibe) {
                const int ib = ibc * 8 + ibe;
                const _Float16* vb = vbase + (size_t)ib * 32768 + jc2 * 8192;
                f16x8 b0[4], b1[4];
                #pragma unroll
                for (int nr = 0; nr < 4; ++nr) b0[nr] = *(const f16x8*)(vb + nr * 128);
                #pragma unroll
                for (int nr = 0; nr < 4; ++nr) b1[nr] = *(const f16x8*)(vb + 4096 + nr * 128);

                #pragma unroll
                for (int mr = 0; mr < 4; ++mr) {
                    const _Float16 s = pis[mr][ibe];
                    f16x8 a0, a1;
                    #pragma unroll
                    for (int e = 0; e < 8; ++e) { a0[e] = pjA[mr][e] * s; a1[e] = pjB[mr][e] * s; }
                    #pragma unroll
                    for (int nr = 0; nr < 4; ++nr)
                        acc[mr][nr] = __builtin_amdgcn_mfma_f32_16x16x32_f16(a0, b0[nr], acc[mr][nr], 0, 0, 0);
                    #pragma unroll
                    for (int nr = 0; nr < 4; ++nr)
                        acc[mr][nr] = __builtin_amdgcn_mfma_f32_16x16x32_f16(a1, b1[nr], acc[mr][nr], 0, 0, 0);
                }
            }
        }
    }

    // last split also does the folded W_w matvec tail: A = P directly
    if (ks == KSPLIT - 1) {
        #pragma unroll 1
        for (int jc = 0; jc < 8; ++jc) {
            const _Float16* vb = Vt + ((size_t)(KBV + jc * 4 + lg) * 128 + coln + l15) * 8;
            f16x8 bfr[4];
            #pragma unroll
            for (int nr = 0; nr < 4; ++nr) bfr[nr] = *(const f16x8*)(vb + nr * 128);
            #pragma unroll
            for (int mr = 0; mr < 4; ++mr) {
                const f16x8 a = *(const f16x8*)&P[rowb + mr * 16 + l15][jc * 32 + lg * 8];
                #pragma unroll
                for (int nr = 0; nr < 4; ++nr)
                    acc[mr][nr] = __builtin_amdgcn_mfma_f32_16x16x32_f16(a, bfr[nr], acc[mr][nr], 0, 0, 0);
            }
        }
    }

    // write fp32 partials; C/D layout: col = lane&15, row = (lane>>4)*4 + q  [m89-verified]
    float* base = part + ((size_t)ks * NB + m0) * DD;
    #pragma unroll
    for (int mr = 0; mr < 4; ++mr)
        #pragma unroll
        for (int nr = 0; nr < 4; ++nr) {
            const int col = coln + nr * 16 + l15;
            #pragma unroll
            for (int q = 0; q < 4; ++q) {
                const int row = rowb + mr * 16 + lg * 4 + q;
                base[(size_t)row * DD + col] = acc[mr][nr][q];
            }
        }
}

// ---------------- epilogue: reduce splits, +W_b, tanh, 5-class logits, log_softmax --------
__global__ void finish(const float* __restrict__ part, const float* __restrict__ Wb,
                       const float* __restrict__ Wsw, const float* __restrict__ Wsb,
                       float* __restrict__ out) {
    int b = blockIdx.x * 256 + threadIdx.x;
    if (b >= NB) return;
    float lg[NCLS];
    #pragma unroll
    for (int c = 0; c < NCLS; ++c) lg[c] = Wsb[c];

    for (int k4 = 0; k4 < DD / 4; ++k4) {
        float4 t = *(const float4*)(Wb + k4 * 4);
        #pragma unroll
        for (int s = 0; s < KSPLIT; ++s) {
            float4 p = *(const float4*)(part + ((size_t)s * NB + b) * DD + k4 * 4);
            t.x += p.x; t.y += p.y; t.z += p.z; t.w += p.w;
        }
        float tq[4] = {t.x, t.y, t.z, t.w};
        #pragma unroll
        for (int q = 0; q < 4; ++q) {
            float h = tanhf(tq[q]);
            int k = k4 * 4 + q;
            #pragma unroll
            for (int c = 0; c < NCLS; ++c)
                lg[c] += h * Wsw[c * DD + k];
        }
    }
    float mx = lg[0];
    #pragma unroll
    for (int c = 1; c < NCLS; ++c) mx = fmaxf(mx, lg[c]);
    float s = 0.f;
    #pragma unroll
    for (int c = 0; c < NCLS; ++c) s += expf(lg[c] - mx);
    float lse = logf(s);
    #pragma unroll
    for (int c = 0; c < NCLS; ++c) out[b * NCLS + c] = lg[c] - mx - lse;
}

extern "C" void kernel_launch(void* const* d_in, const int* in_sizes, int n_in,
                              void* d_out, int out_size, void* d_ws, size_t ws_size,
                              hipStream_t stream) {
    const float* left  = (const float*)d_in[0];
    const float* right = (const float*)d_in[1];
    const float* V     = (const float*)d_in[2];
    const float* Ww    = (const float*)d_in[3];
    const float* Wb    = (const float*)d_in[4];
    const float* Wsw   = (const float*)d_in[5];
    const float* Wsb   = (const float*)d_in[6];
    float* out = (float*)d_out;

    _Float16* Vt = (_Float16*)d_ws;                                  // 16,842,752 B
    float* part  = (float*)((char*)d_ws + (size_t)KBTOT * 1024 * 2); // 33,554,432 B

    hipLaunchKernelGGL(prep_vt, dim3((KBTOT * DD) / 256), dim3(256), 0, stream, V, Ww, Vt);
    hipLaunchKernelGGL(gemm_bilinear, dim3((NB / BM) * KSPLIT), dim3(256), 0, stream,
                       left, right, Vt, part);
    hipLaunchKernelGGL(finish, dim3(NB / 256), dim3(256), 0, stream, part, Wb, Wsw, Wsb, out);
}